// Round 8
// baseline (25.813 us; speedup 1.0000x reference)
//
#include <hip/hip_runtime.h>

#define BATCH 4096
#define FEAT  2048

typedef float f32x4 __attribute__((ext_vector_type(4)));

// DIAGNOSTIC ROUND: exact R4 kernels; k1 launched TWICE (idempotent) so
// dur_us - 16.0 gives k1's marginal cost, splitting k1 vs (k2 + node gap).

// kernel 1: one WAVE per batch row. 1024 blocks x 256 threads (4 waves/block).
__global__ __launch_bounds__(256) void center_loss_rows(
        const float* __restrict__ x,
        const int*   __restrict__ labels,
        const float* __restrict__ centers,
        float*       __restrict__ row_dist) {
    const int wave = threadIdx.x >> 6;
    const int lane = threadIdx.x & 63;
    const int row  = (blockIdx.x << 2) | wave;

    const int lbl = labels[row];                      // wave-uniform -> scalar load
    const f32x4* __restrict__ xr = (const f32x4*)(x + (size_t)row * FEAT) + lane;
    const f32x4* __restrict__ cr = (const f32x4*)(centers + (size_t)lbl * FEAT) + lane;

    f32x4 xv[8], cv[8];
#pragma unroll
    for (int i = 0; i < 8; ++i)
        xv[i] = __builtin_nontemporal_load(xr + (i << 6));   // x: streamed
#pragma unroll
    for (int i = 0; i < 8; ++i)
        cv[i] = cr[i << 6];                                   // centers: cacheable

    float p = 0.f;
#pragma unroll
    for (int i = 0; i < 8; ++i) {
        f32x4 d = xv[i] - cv[i];
        p += d.x * d.x + d.y * d.y + d.z * d.z + d.w * d.w;
    }

#pragma unroll
    for (int off = 32; off > 0; off >>= 1)
        p += __shfl_down(p, off, 64);

    if (lane == 0)
        row_dist[row] = fminf(fmaxf(p, 1e-12f), 1e12f);
}

// kernel 2: single block reduces the 4096 row dists -> mean
__global__ __launch_bounds__(256) void reduce_mean_kernel(
        const float* __restrict__ row_dist,
        float*       __restrict__ out) {
    const int t = threadIdx.x;
    const f32x4* __restrict__ rd = (const f32x4*)row_dist;

    float s = 0.f;
#pragma unroll
    for (int i = 0; i < BATCH / 4 / 256; ++i) {
        f32x4 v = rd[t + i * 256];
        s += v.x + v.y + v.z + v.w;
    }

#pragma unroll
    for (int off = 32; off > 0; off >>= 1)
        s += __shfl_down(s, off, 64);

    __shared__ float sw[4];
    if ((t & 63) == 0) sw[t >> 6] = s;
    __syncthreads();

    if (t == 0)
        out[0] = (sw[0] + sw[1] + sw[2] + sw[3]) * (1.0f / (float)BATCH);
}

extern "C" void kernel_launch(void* const* d_in, const int* in_sizes, int n_in,
                              void* d_out, int out_size, void* d_ws, size_t ws_size,
                              hipStream_t stream) {
    const float* x       = (const float*)d_in[0];
    const int*   labels  = (const int*)d_in[1];
    const float* centers = (const float*)d_in[2];
    float* out = (float*)d_out;
    float* row_dist = (float*)d_ws;   // BATCH floats = 16 KB scratch

    center_loss_rows<<<BATCH / 4, 256, 0, stream>>>(x, labels, centers, row_dist);
    center_loss_rows<<<BATCH / 4, 256, 0, stream>>>(x, labels, centers, row_dist); // diagnostic dup
    reduce_mean_kernel<<<1, 256, 0, stream>>>(row_dist, out);
}

// Round 9
// 15.647 us; speedup vs baseline: 1.6496x; 1.6496x over previous
//
#include <hip/hip_runtime.h>

#define BATCH 4096
#define FEAT  2048
#define GRID  1024   // 4 rows per block (one per wave)

typedef float f32x4 __attribute__((ext_vector_type(4)));

// kernel 1: one WAVE per batch row; block emits ONE partial (sum of its 4
// clamped row dists). k1 is fabric-bound (R8 diagnostic: 9.8us for 64MB
// demand = 6.5 TB/s aggregate ~ observed ceiling), so only the epilogue changed.
__global__ __launch_bounds__(256) void center_loss_rows(
        const float* __restrict__ x,
        const int*   __restrict__ labels,
        const float* __restrict__ centers,
        float*       __restrict__ partials) {
    const int wave = threadIdx.x >> 6;
    const int lane = threadIdx.x & 63;
    const int row  = (blockIdx.x << 2) | wave;

    const int lbl = labels[row];                      // wave-uniform -> scalar load
    const f32x4* __restrict__ xr = (const f32x4*)(x + (size_t)row * FEAT) + lane;
    const f32x4* __restrict__ cr = (const f32x4*)(centers + (size_t)lbl * FEAT) + lane;

    // issue all 16 loads before any arithmetic
    f32x4 xv[8], cv[8];
#pragma unroll
    for (int i = 0; i < 8; ++i)
        xv[i] = __builtin_nontemporal_load(xr + (i << 6));   // x: streamed (keeps L2 for centers)
#pragma unroll
    for (int i = 0; i < 8; ++i)
        cv[i] = cr[i << 6];                                   // centers: cacheable (L2/L3 resident)

    float p = 0.f;
#pragma unroll
    for (int i = 0; i < 8; ++i) {
        f32x4 d = xv[i] - cv[i];
        p += d.x * d.x + d.y * d.y + d.z * d.z + d.w * d.w;
    }

    // wave-64 butterfly reduce
#pragma unroll
    for (int off = 32; off > 0; off >>= 1)
        p += __shfl_down(p, off, 64);

    __shared__ float sw[4];
    if (lane == 0) sw[wave] = p;
    __syncthreads();

    if (threadIdx.x == 0) {
        // clamp per ROW (reference semantics), then sum the block's 4 rows
        float s = fminf(fmaxf(sw[0], 1e-12f), 1e12f)
                + fminf(fmaxf(sw[1], 1e-12f), 1e12f)
                + fminf(fmaxf(sw[2], 1e-12f), 1e12f)
                + fminf(fmaxf(sw[3], 1e-12f), 1e12f);
        partials[blockIdx.x] = s;
    }
}

// kernel 2: ONE wave reduces 1024 partials (4 KB) -> mean. No LDS, no sync.
__global__ __launch_bounds__(64) void reduce_mean_kernel(
        const float* __restrict__ partials,
        float*       __restrict__ out) {
    const int lane = threadIdx.x;
    const f32x4* __restrict__ pp = (const f32x4*)partials;   // 256 x f32x4

    float s = 0.f;
#pragma unroll
    for (int i = 0; i < 4; ++i) {                   // 4 f32x4 per lane
        f32x4 v = pp[lane + (i << 6)];
        s += v.x + v.y + v.z + v.w;
    }

#pragma unroll
    for (int off = 32; off > 0; off >>= 1)
        s += __shfl_down(s, off, 64);

    if (lane == 0)
        out[0] = s * (1.0f / (float)BATCH);
}

extern "C" void kernel_launch(void* const* d_in, const int* in_sizes, int n_in,
                              void* d_out, int out_size, void* d_ws, size_t ws_size,
                              hipStream_t stream) {
    const float* x       = (const float*)d_in[0];
    const int*   labels  = (const int*)d_in[1];
    const float* centers = (const float*)d_in[2];
    float* out = (float*)d_out;
    float* partials = (float*)d_ws;   // GRID floats = 4 KB scratch

    center_loss_rows<<<GRID, 256, 0, stream>>>(x, labels, centers, partials);
    reduce_mean_kernel<<<1, 64, 0, stream>>>(partials, out);
}